// Round 1
// baseline (192.958 us; speedup 1.0000x reference)
//
#include <hip/hip_runtime.h>

static constexpr int N = 4096;
static constexpr int D = 8192;
static constexpr int BLOCK = 256;
static constexpr int RPB = 4;          // rows per block (persistent, pipelined)
static constexpr int GRID = N / RPB;   // 1024 blocks = 4 blocks/CU, fully co-resident

// Load one row (32 KB) as 8 x float4 per thread. 8 loads in flight per call.
__device__ __forceinline__ void load_row(float4 (&v)[8], const float* __restrict__ emb,
                                         int row, int tid)
{
    const float4* rowp = reinterpret_cast<const float4*>(emb + (size_t)row * D);
    #pragma unroll
    for (int it = 0; it < 8; ++it)
        v[it] = rowp[tid + it * BLOCK];
}

// Same math as the verified kernel, bit-identical accumulation order.
__device__ __forceinline__ void compute_row(const float4 (&v)[8], const int4 (&lj)[4],
                                            int lab_i, int row, int tid, int r,
                                            float (*s_red)[4][4])
{
    float denom = 0.f, ssum = 0.f, diag = 0.f, fcnt = 0.f;

    // First half: j in [0, N) -> denom + masked B-sum + count + diagonal
    #pragma unroll
    for (int it = 0; it < 4; ++it) {
        const int j0 = (tid + it * BLOCK) * 4;
        float xs[4] = {v[it].x, v[it].y, v[it].z, v[it].w};
        int   ls[4] = {lj[it].x, lj[it].y, lj[it].z, lj[it].w};
        #pragma unroll
        for (int k = 0; k < 4; ++k) {
            float a = __expf(xs[k] * xs[k] * 0.1f);
            denom += a;
            float b = __expf(a * 0.1f);              // unconditional: no divergence
            bool match = (ls[k] == lab_i) && (j0 + k != row);
            ssum += match ? b : 0.f;
            fcnt += match ? 1.f : 0.f;
            diag += (j0 + k == row) ? a : 0.f;
        }
    }
    // Second half: j in [N, D) -> denom only
    #pragma unroll
    for (int it = 4; it < 8; ++it) {
        float xs[4] = {v[it].x, v[it].y, v[it].z, v[it].w};
        #pragma unroll
        for (int k = 0; k < 4; ++k)
            denom += __expf(xs[k] * xs[k] * 0.1f);
    }

    // wave-64 shuffle reduction (lane 0 holds the wave sum)
    #pragma unroll
    for (int off = 32; off > 0; off >>= 1) {
        denom += __shfl_down(denom, off);
        ssum  += __shfl_down(ssum,  off);
        diag  += __shfl_down(diag,  off);
        fcnt  += __shfl_down(fcnt,  off);
    }
    const int wave = tid >> 6;
    if ((tid & 63) == 0) {
        s_red[r][0][wave] = denom;
        s_red[r][1][wave] = ssum;
        s_red[r][2][wave] = diag;
        s_red[r][3][wave] = fcnt;
    }
    // NOTE: no __syncthreads here — a barrier would s_waitcnt vmcnt(0) and
    // drain the next row's prefetch loads. One barrier at the end only.
}

__global__ __launch_bounds__(BLOCK, 4) void supcon_rows(
    const float* __restrict__ emb,
    const int* __restrict__ labels,
    float* __restrict__ row_out)
{
    __shared__ float s_red[RPB][4][4];   // [row][quantity][wave]
    const int tid  = threadIdx.x;
    const int row0 = blockIdx.x * RPB;

    // Labels: loaded once per block, reused for all 4 rows.
    const int4* labp = reinterpret_cast<const int4*>(labels);
    int4 lj[4];
    #pragma unroll
    for (int it = 0; it < 4; ++it)
        lj[it] = labp[tid + it * BLOCK];

    int labr[RPB];                        // wave-uniform -> s_load
    #pragma unroll
    for (int r = 0; r < RPB; ++r)
        labr[r] = labels[row0 + r];

    // Software pipeline: prefetch row k+1 before computing row k.
    // Explicit two-buffer ping-pong, all indices compile-time static.
    float4 va[8], vb[8];
    load_row(va, emb, row0 + 0, tid);
    load_row(vb, emb, row0 + 1, tid);

    compute_row(va, lj, labr[0], row0 + 0, tid, 0, s_red);
    load_row(va, emb, row0 + 2, tid);
    compute_row(vb, lj, labr[1], row0 + 1, tid, 1, s_red);
    load_row(vb, emb, row0 + 3, tid);
    compute_row(va, lj, labr[2], row0 + 2, tid, 2, s_red);
    compute_row(vb, lj, labr[3], row0 + 3, tid, 3, s_red);

    __syncthreads();
    if (tid < RPB) {
        float dn = 0.f, sv = 0.f, dg = 0.f, c = 0.f;
        #pragma unroll
        for (int w = 0; w < 4; ++w) {
            dn += s_red[tid][0][w];
            sv += s_red[tid][1][w];
            dg += s_red[tid][2][w];
            c  += s_red[tid][3][w];
        }
        dn -= dg;   // denom_i = sum_d A[i,d] - A[i,i]
        row_out[row0 + tid] = __logf(sv) - __logf(dn) - __logf(c);
    }
}

// 4096 row values -> scalar, one block of 1024 threads (unchanged, deterministic)
__global__ __launch_bounds__(1024) void reduce_rows(
    const float* __restrict__ row_vals, float* __restrict__ out)
{
    const int tid = threadIdx.x;
    float4 x = reinterpret_cast<const float4*>(row_vals)[tid];
    float s = x.x + x.y + x.z + x.w;
    #pragma unroll
    for (int off = 32; off > 0; off >>= 1)
        s += __shfl_down(s, off);
    __shared__ float sb[16];
    if ((tid & 63) == 0) sb[tid >> 6] = s;
    __syncthreads();
    if (tid == 0) {
        float t = 0.f;
        #pragma unroll
        for (int w = 0; w < 16; ++w) t += sb[w];
        *out = t;
    }
}

extern "C" void kernel_launch(void* const* d_in, const int* in_sizes, int n_in,
                              void* d_out, int out_size, void* d_ws, size_t ws_size,
                              hipStream_t stream) {
    const float* emb  = (const float*)d_in[0];
    const int* labels = (const int*)d_in[1];
    float* out        = (float*)d_out;
    float* row_vals   = (float*)d_ws;   // 4096 floats = 16 KB scratch

    supcon_rows<<<dim3(GRID), dim3(BLOCK), 0, stream>>>(emb, labels, row_vals);
    reduce_rows<<<dim3(1), dim3(1024), 0, stream>>>(row_vals, out);
}